// Round 4
// baseline (384.047 us; speedup 1.0000x reference)
//
#include <hip/hip_runtime.h>
#include <math.h>

#define HH 512
#define WW 512

typedef short bf16x8 __attribute__((ext_vector_type(8)));
typedef float f32x4 __attribute__((ext_vector_type(4)));

__device__ __forceinline__ ushort f2bf(float f) {
    union { float f; uint u; } c; c.f = f;
    uint u = c.u;
    return (ushort)((u + 0x7fffu + ((u >> 16) & 1u)) >> 16);
}

// ---------------- kernel 1: styles = ws @ (aw.T / sqrt(512)) + ab ----------------
__global__ void k_styles(const float* __restrict__ wsv,      // [B,512]
                         const float* __restrict__ aw,       // [64,512]
                         const float* __restrict__ ab,       // [64]
                         float* __restrict__ styles) {       // [B,64]
    int bid = blockIdx.x;
    int b = bid >> 6, ci = bid & 63;
    int l = threadIdx.x;
    const float* wrow = wsv + b * 512;
    const float* arow = aw + ci * 512;
    float s = 0.f;
    #pragma unroll
    for (int j = 0; j < 8; ++j)
        s += wrow[l + 64 * j] * arow[l + 64 * j];
    #pragma unroll
    for (int off = 32; off; off >>= 1)
        s += __shfl_xor(s, off, 64);
    if (l == 0)
        styles[b * 64 + ci] = s * 0.044194173824159216f + ab[ci];
}

// ------------- kernel 2: modulate + demodulate -> bf16 [b][k(9)][co][ci] -------------
__global__ void k_wmod(const float* __restrict__ cw,      // [64,64,3,3]
                       const float* __restrict__ styles,  // [B,64]
                       ushort* __restrict__ wb) {         // [B,9,64,64] bf16
    int b = blockIdx.x >> 6, co = blockIdx.x & 63;
    int ci = threadIdx.x;   // one wave
    float st = styles[b * 64 + ci];
    const float* wp = cw + (co * 64 + ci) * 9;
    float wv[9];
    float ss = 0.f;
    #pragma unroll
    for (int k = 0; k < 9; ++k) { wv[k] = wp[k] * st; ss += wv[k] * wv[k]; }
    #pragma unroll
    for (int off = 32; off; off >>= 1)
        ss += __shfl_xor(ss, off, 64);
    float dm = 1.0f / sqrtf(ss + 1e-8f);
    #pragma unroll
    for (int k = 0; k < 9; ++k)
        wb[((size_t)(b * 9 + k) * 64 + co) * 64 + ci] = f2bf(wv[k] * dm);
}

// ------------- kernel 3: MFMA implicit-GEMM conv + epilogue -------------
// Block: 512 threads (8 waves). Output tile: 64 co x (8 rows x 32 cols).
// Wave w owns output row w; i in {0,1} selects the 16-px column half.
// LDS: x tile [lrow 10][lcol 34][ci 64] bf16.
// Swizzle: ci-block index XORed by f(lcol)<<3, f = (lcol ^ (lcol>>2)) & 7
//   -> distinct across adjacent lanes in g-fastest staging order (write-
//      conflict-free) AND across consecutive lcol (read 2-way = free).
// Staging task order: g (col group) lane-fastest -> wave reads contiguous
// row segments within ONE ci plane per instruction (DRAM locality).
__global__ __launch_bounds__(512, 6) void k_conv(
    const float* __restrict__ x,      // [B,64,512,512] fp32
    const ushort* __restrict__ wb,    // [B,9,64,64] bf16
    const float* __restrict__ noise,  // [B,1,512,512]
    const float* __restrict__ bias,   // [64]
    float* __restrict__ out) {        // [B,64,512,512] fp32
    __shared__ ushort xt[10 * 34 * 64];   // 43520 B

    const int t = threadIdx.x;
    const int b = blockIdx.y;
    const int colb = blockIdx.x & 15;
    const int rowb = blockIdx.x >> 4;
    const int tx = colb * 32, ty = rowb * 8;

    const float* xb = x + (size_t)b * 64 * (HH * WW);

    // ---- staging: 1600 tasks = cg(16) x lrow(10) x g(10), g lane-fastest ----
    #pragma unroll
    for (int r = 0; r < 4; ++r) {
        int id = t + r * 512;
        if (id < 1600) {
            int g = id % 10;
            int tmp = id / 10;
            int lrow = tmp % 10;
            int cg = tmp / 10;         // 0..15 (group of 4 ci planes)
            int gy = ty - 1 + lrow;
            int gx0 = tx - 4 + g * 4;  // 16B-aligned float4 window
            f32x4 v[4];
            bool ok = (gy >= 0) && (gy < HH) && (gx0 >= 0) && (gx0 <= WW - 4);
            if (ok) {
                const float* p = xb + (size_t)(cg * 4) * (HH * WW) + (size_t)gy * WW + gx0;
                #pragma unroll
                for (int i = 0; i < 4; ++i)
                    v[i] = *(const f32x4*)(p + (size_t)i * (HH * WW));
            } else {
                #pragma unroll
                for (int i = 0; i < 4; ++i) v[i] = (f32x4){0.f, 0.f, 0.f, 0.f};
            }
            #pragma unroll
            for (int e = 0; e < 4; ++e) {
                int lcol = g * 4 + e - 3;
                if (lcol >= 0 && lcol < 34) {
                    uint lo = (uint)f2bf(v[0][e]) | ((uint)f2bf(v[1][e]) << 16);
                    uint hi = (uint)f2bf(v[2][e]) | ((uint)f2bf(v[3][e]) << 16);
                    int fc = (lcol ^ (lcol >> 2)) & 7;
                    int cib = (cg * 4) ^ (fc << 3);
                    uint2* dst = (uint2*)&xt[(lrow * 34 + lcol) * 64 + cib];
                    *dst = make_uint2(lo, hi);
                }
            }
        }
    }
    __syncthreads();

    // ---- compute ----
    const int w = t >> 6;          // wave 0..7 = output row within tile
    const int lane = t & 63;
    const int lr = lane & 15;
    const int lq = lane >> 4;

    // B-frag base LDS indices (dy=0, kb=0) for i (col half) x dx
    int bidx[2][3];
    #pragma unroll
    for (int i = 0; i < 2; ++i) {
        int c = i * 16 + lr;
        #pragma unroll
        for (int dx = 0; dx < 3; ++dx) {
            int lcol = c + dx;
            int fc = (lcol ^ (lcol >> 2)) & 7;
            bidx[i][dx] = (w * 34 + lcol) * 64 + ((lq * 8) ^ (fc << 3));
        }
    }

    const ushort* wbb = wb + (size_t)b * 9 * 64 * 64 + lr * 64 + lq * 8;

    f32x4 acc[4][2];
    #pragma unroll
    for (int m = 0; m < 4; ++m)
        #pragma unroll
        for (int i = 0; i < 2; ++i) acc[m][i] = (f32x4){0.f, 0.f, 0.f, 0.f};

    #pragma unroll
    for (int dy = 0; dy < 3; ++dy) {
        #pragma unroll
        for (int dx = 0; dx < 3; ++dx) {
            #pragma unroll
            for (int kb = 0; kb < 2; ++kb) {
                const int off = dy * 3 + dx;
                bf16x8 afr[4], bfr[2];
                #pragma unroll
                for (int m = 0; m < 4; ++m)
                    afr[m] = *(const bf16x8*)(wbb + off * 4096 + m * 1024 + kb * 32);
                #pragma unroll
                for (int i = 0; i < 2; ++i) {
                    int idx = (bidx[i][dx] + dy * (34 * 64)) ^ (kb * 32);
                    bfr[i] = *(const bf16x8*)&xt[idx];
                }
                #pragma unroll
                for (int m = 0; m < 4; ++m)
                    #pragma unroll
                    for (int i = 0; i < 2; ++i)
                        acc[m][i] = __builtin_amdgcn_mfma_f32_16x16x32_bf16(
                            afr[m], bfr[i], acc[m][i], 0, 0, 0);
            }
        }
    }

    // ---- epilogue: +noise, +bias, lrelu*sqrt2, clamp, store ----
    const float* nz = noise + (size_t)b * (HH * WW);
    float nv[2];
    int gyv[2], gxv[2];
    #pragma unroll
    for (int i = 0; i < 2; ++i) {
        gyv[i] = ty + w;
        gxv[i] = tx + i * 16 + lr;
        nv[i] = nz[gyv[i] * WW + gxv[i]];
    }
    #pragma unroll
    for (int m = 0; m < 4; ++m) {
        f32x4 bv = *(const f32x4*)&bias[m * 16 + lq * 4];
        #pragma unroll
        for (int i = 0; i < 2; ++i) {
            #pragma unroll
            for (int rg2 = 0; rg2 < 4; ++rg2) {
                int co = m * 16 + lq * 4 + rg2;
                float y = acc[m][i][rg2] + nv[i] + bv[rg2];
                y = (y >= 0.f ? y : 0.2f * y) * 1.41421356237f;
                y = fminf(fmaxf(y, -256.f), 256.f);
                out[((size_t)(b * 64 + co) * HH + gyv[i]) * WW + gxv[i]] = y;
            }
        }
    }
}

extern "C" void kernel_launch(void* const* d_in, const int* in_sizes, int n_in,
                              void* d_out, int out_size, void* d_ws, size_t ws_size,
                              hipStream_t stream) {
    const float* x     = (const float*)d_in[0];
    const float* wsv   = (const float*)d_in[1];
    const float* noise = (const float*)d_in[2];
    const float* aw    = (const float*)d_in[3];
    const float* ab    = (const float*)d_in[4];
    const float* cw    = (const float*)d_in[5];
    const float* bias  = (const float*)d_in[6];
    float* out = (float*)d_out;

    float*  styles = (float*)d_ws;                       // 256 floats
    ushort* wb16   = (ushort*)((char*)d_ws + 1024);      // 4*9*64*64 bf16 = 294912 B

    k_styles<<<256, 64, 0, stream>>>(wsv, aw, ab, styles);
    k_wmod<<<256, 64, 0, stream>>>(cw, styles, wb16);
    dim3 grid(1024, 4);
    k_conv<<<grid, 512, 0, stream>>>(x, wb16, noise, bias, out);
}

// Round 5
// 368.032 us; speedup vs baseline: 1.0435x; 1.0435x over previous
//
#include <hip/hip_runtime.h>
#include <math.h>

#define HH 512
#define WW 512
#define HW (HH * WW)

typedef short bf16x8 __attribute__((ext_vector_type(8)));
typedef float f32x4 __attribute__((ext_vector_type(4)));

__device__ __forceinline__ ushort f2bf(float f) {
    union { float f; uint u; } c; c.f = f;
    uint u = c.u;
    return (ushort)((u + 0x7fffu + ((u >> 16) & 1u)) >> 16);
}

// ---------------- kernel 1: styles = ws @ (aw.T / sqrt(512)) + ab ----------------
__global__ void k_styles(const float* __restrict__ wsv,      // [B,512]
                         const float* __restrict__ aw,       // [64,512]
                         const float* __restrict__ ab,       // [64]
                         float* __restrict__ styles) {       // [B,64]
    int bid = blockIdx.x;
    int b = bid >> 6, ci = bid & 63;
    int l = threadIdx.x;
    const float* wrow = wsv + b * 512;
    const float* arow = aw + ci * 512;
    float s = 0.f;
    #pragma unroll
    for (int j = 0; j < 8; ++j)
        s += wrow[l + 64 * j] * arow[l + 64 * j];
    #pragma unroll
    for (int off = 32; off; off >>= 1)
        s += __shfl_xor(s, off, 64);
    if (l == 0)
        styles[b * 64 + ci] = s * 0.044194173824159216f + ab[ci];
}

// ------------- kernel 2: modulate + demodulate -> bf16 [b][k(9)][co][ci] -------------
__global__ void k_wmod(const float* __restrict__ cw,      // [64,64,3,3]
                       const float* __restrict__ styles,  // [B,64]
                       ushort* __restrict__ wb) {         // [B,9,64,64] bf16
    int b = blockIdx.x >> 6, co = blockIdx.x & 63;
    int ci = threadIdx.x;   // one wave
    float st = styles[b * 64 + ci];
    const float* wp = cw + (co * 64 + ci) * 9;
    float wv[9];
    float ss = 0.f;
    #pragma unroll
    for (int k = 0; k < 9; ++k) { wv[k] = wp[k] * st; ss += wv[k] * wv[k]; }
    #pragma unroll
    for (int off = 32; off; off >>= 1)
        ss += __shfl_xor(ss, off, 64);
    float dm = 1.0f / sqrtf(ss + 1e-8f);
    #pragma unroll
    for (int k = 0; k < 9; ++k)
        wb[((size_t)(b * 9 + k) * 64 + co) * 64 + ci] = f2bf(wv[k] * dm);
}

// ------------- kernel 3: MFMA implicit-GEMM conv + epilogue -------------
// Block: 256 threads (4 waves). Output tile: 64 co x (8 rows x 32 cols).
// Staging: 4 ci-chunks of 16 planes via global_load_lds (fp32, linear LDS
// buf [16][10][40]) -> deep MLP, no VGPR round-trip. Then in-LDS transpose/
// convert pass into bf16 tile [row 10][col 34][ci 64], ci XOR-swizzled by
// (lcol&7)<<3 (R2-proven: 0 read conflicts).
// Compute: R2-proven 4-wave mapping, wave w -> n-tiles {4w..4w+3}, all 4 m.
__global__ __launch_bounds__(256, 2) void k_conv(
    const float* __restrict__ x,      // [B,64,512,512] fp32
    const ushort* __restrict__ wb,    // [B,9,64,64] bf16
    const float* __restrict__ noise,  // [B,1,512,512]
    const float* __restrict__ bias,   // [64]
    float* __restrict__ out) {        // [B,64,512,512] fp32
    __shared__ ushort tile[10 * 34 * 64];   // 43520 B
    __shared__ float  buf[16 * 10 * 40];    // 25600 B (one 16-ci chunk, fp32)

    const int t = threadIdx.x;
    const int b = blockIdx.y;
    const int colb = blockIdx.x & 15;
    const int rowb = blockIdx.x >> 4;
    const int tx = colb * 32, ty = rowb * 8;
    const int w = t >> 6;
    const int lane = t & 63;

    const float* xb = x + (size_t)b * 64 * HW;

    // ================= staging: 4 chunks of 16 ci planes =================
    for (int cc = 0; cc < 4; ++cc) {
        // --- issue global_load_lds: 25 x 1KB per block, split across waves ---
        for (int k = w; k < 25; k += 4) {
            int f = k * 256 + 4 * lane;        // dword index into buf
            int ci = f / 400;                  // 400 dwords per plane-row-buf
            int rem = f - ci * 400;
            int row = rem / 40;
            int col = rem - row * 40;
            int gy = ty - 1 + row;  gy = gy < 0 ? 0 : (gy > 511 ? 511 : gy);
            int gx = tx - 4 + col;  gx = gx < 0 ? 0 : (gx > 508 ? 508 : gx);
            const float* src = xb + (size_t)(cc * 16 + ci) * HW + gy * WW + gx;
            __builtin_amdgcn_global_load_lds(
                (const __attribute__((address_space(1))) unsigned int*)src,
                (__attribute__((address_space(3))) unsigned int*)&buf[k * 256],
                16, 0, 0);
        }
        asm volatile("s_waitcnt vmcnt(0)" ::: "memory");
        __syncthreads();

        // --- convert/transpose: buf fp32 -> bf16 tile slice (16 ci) ---
        #pragma unroll
        for (int q = 0; q < 3; ++q) {
            int id = t + q * 256;
            if (id < 680) {                    // 10 rows x 34 cols x 2 ci-groups
                int lcol = id % 34;
                int rem = id / 34;
                int cs = rem & 1;              // ci-group of 8 within chunk
                int row = rem >> 1;
                int gy = ty - 1 + row;
                int gxl = tx - 1 + lcol;
                bool ok = (gy >= 0) && (gy < HH) && (gxl >= 0) && (gxl < WW);
                int base = (8 * cs) * 400 + row * 40 + (lcol + 3);
                float v[8];
                #pragma unroll
                for (int j = 0; j < 8; ++j)
                    v[j] = ok ? buf[base + j * 400] : 0.f;
                uint pk[4];
                #pragma unroll
                for (int j = 0; j < 4; ++j)
                    asm("v_cvt_pk_bf16_f32 %0, %1, %2"
                        : "=v"(pk[j]) : "v"(v[2 * j]), "v"(v[2 * j + 1]));
                int grp = ((2 * cc + cs) ^ (lcol & 7)) << 3;   // swizzled 8-ci group
                uint4* dst = (uint4*)&tile[(row * 34 + lcol) * 64 + grp];
                *dst = make_uint4(pk[0], pk[1], pk[2], pk[3]);
            }
        }
        __syncthreads();
    }

    // ================= MFMA phase (R2-proven) =================
    const int lr = lane & 15;
    const int lq = lane >> 4;

    int bidx[4][3];
    #pragma unroll
    for (int i = 0; i < 4; ++i) {
        int nt = 4 * w + i;
        int prow = nt >> 1;
        int c = (nt & 1) * 16 + lr;
        #pragma unroll
        for (int dx = 0; dx < 3; ++dx) {
            int lcol = c + dx;
            bidx[i][dx] = (prow * 34 + lcol) * 64 + ((lq * 8) ^ ((lcol & 7) << 3));
        }
    }

    const ushort* wbb = wb + (size_t)b * 9 * 4096 + lr * 64 + lq * 8;

    f32x4 acc[4][4];
    #pragma unroll
    for (int m = 0; m < 4; ++m)
        #pragma unroll
        for (int i = 0; i < 4; ++i) acc[m][i] = (f32x4){0.f, 0.f, 0.f, 0.f};

    #pragma unroll
    for (int dy = 0; dy < 3; ++dy) {
        #pragma unroll
        for (int dx = 0; dx < 3; ++dx) {
            #pragma unroll
            for (int kb = 0; kb < 2; ++kb) {
                const int off = dy * 3 + dx;
                bf16x8 afr[4], bfr[4];
                #pragma unroll
                for (int m = 0; m < 4; ++m)
                    afr[m] = *(const bf16x8*)(wbb + off * 4096 + m * 1024 + kb * 32);
                #pragma unroll
                for (int i = 0; i < 4; ++i) {
                    int idx = (bidx[i][dx] + dy * (34 * 64)) ^ (kb << 5);
                    bfr[i] = *(const bf16x8*)&tile[idx];
                }
                #pragma unroll
                for (int m = 0; m < 4; ++m)
                    #pragma unroll
                    for (int i = 0; i < 4; ++i)
                        acc[m][i] = __builtin_amdgcn_mfma_f32_16x16x32_bf16(
                            afr[m], bfr[i], acc[m][i], 0, 0, 0);
            }
        }
    }

    // ---- epilogue: +noise, +bias, lrelu*sqrt2, clamp, store ----
    const float* nz = noise + (size_t)b * HW;
    float nv[4];
    int gyv[4], gxv[4];
    #pragma unroll
    for (int i = 0; i < 4; ++i) {
        int nt = 4 * w + i;
        int prow = nt >> 1;
        int pcol = (nt & 1) * 16 + lr;
        gyv[i] = ty + prow;
        gxv[i] = tx + pcol;
        nv[i] = nz[gyv[i] * WW + gxv[i]];
    }
    #pragma unroll
    for (int m = 0; m < 4; ++m) {
        f32x4 bv = *(const f32x4*)&bias[m * 16 + lq * 4];
        #pragma unroll
        for (int i = 0; i < 4; ++i) {
            #pragma unroll
            for (int rg2 = 0; rg2 < 4; ++rg2) {
                int co = m * 16 + lq * 4 + rg2;
                float y = acc[m][i][rg2] + nv[i] + bv[rg2];
                y = (y >= 0.f ? y : 0.2f * y) * 1.41421356237f;
                y = fminf(fmaxf(y, -256.f), 256.f);
                out[((size_t)(b * 64 + co) * HH + gyv[i]) * WW + gxv[i]] = y;
            }
        }
    }
}

extern "C" void kernel_launch(void* const* d_in, const int* in_sizes, int n_in,
                              void* d_out, int out_size, void* d_ws, size_t ws_size,
                              hipStream_t stream) {
    const float* x     = (const float*)d_in[0];
    const float* wsv   = (const float*)d_in[1];
    const float* noise = (const float*)d_in[2];
    const float* aw    = (const float*)d_in[3];
    const float* ab    = (const float*)d_in[4];
    const float* cw    = (const float*)d_in[5];
    const float* bias  = (const float*)d_in[6];
    float* out = (float*)d_out;

    float*  styles = (float*)d_ws;                       // 256 floats
    ushort* wb16   = (ushort*)((char*)d_ws + 1024);      // 4*9*64*64 bf16 = 294912 B

    k_styles<<<256, 64, 0, stream>>>(wsv, aw, ab, styles);
    k_wmod<<<256, 64, 0, stream>>>(cw, styles, wb16);
    dim3 grid(1024, 4);
    k_conv<<<grid, 256, 0, stream>>>(x, wb16, noise, bias, out);
}

// Round 6
// 309.405 us; speedup vs baseline: 1.2412x; 1.1895x over previous
//
#include <hip/hip_runtime.h>
#include <math.h>

#define HH 512
#define WW 512
#define HW (HH * WW)
#define PW 514                    // padded width/height
#define PPIX (PW * PW)            // pixels per padded plane-set

typedef short bf16x8 __attribute__((ext_vector_type(8)));
typedef float f32x4 __attribute__((ext_vector_type(4)));

__device__ __forceinline__ ushort f2bf(float f) {
    union { float f; uint u; } c; c.f = f;
    uint u = c.u;
    return (ushort)((u + 0x7fffu + ((u >> 16) & 1u)) >> 16);
}

__device__ __forceinline__ uint cvtpk(float a, float b) {
    uint r;
    asm("v_cvt_pk_bf16_f32 %0, %1, %2" : "=v"(r) : "v"(a), "v"(b));
    return r;
}

// ---------------- kernel 1: styles = ws @ (aw.T / sqrt(512)) + ab ----------------
__global__ void k_styles(const float* __restrict__ wsv, const float* __restrict__ aw,
                         const float* __restrict__ ab, float* __restrict__ styles) {
    int bid = blockIdx.x;
    int b = bid >> 6, ci = bid & 63;
    int l = threadIdx.x;
    const float* wrow = wsv + b * 512;
    const float* arow = aw + ci * 512;
    float s = 0.f;
    #pragma unroll
    for (int j = 0; j < 8; ++j)
        s += wrow[l + 64 * j] * arow[l + 64 * j];
    #pragma unroll
    for (int off = 32; off; off >>= 1)
        s += __shfl_xor(s, off, 64);
    if (l == 0)
        styles[b * 64 + ci] = s * 0.044194173824159216f + ab[ci];
}

// ------------- kernel 2: modulate + demodulate -> bf16 [b][k(9)][co][ci] -------------
__global__ void k_wmod(const float* __restrict__ cw, const float* __restrict__ styles,
                       ushort* __restrict__ wb) {
    int b = blockIdx.x >> 6, co = blockIdx.x & 63;
    int ci = threadIdx.x;
    float st = styles[b * 64 + ci];
    const float* wp = cw + (co * 64 + ci) * 9;
    float wv[9];
    float ss = 0.f;
    #pragma unroll
    for (int k = 0; k < 9; ++k) { wv[k] = wp[k] * st; ss += wv[k] * wv[k]; }
    #pragma unroll
    for (int off = 32; off; off >>= 1)
        ss += __shfl_xor(ss, off, 64);
    float dm = 1.0f / sqrtf(ss + 1e-8f);
    #pragma unroll
    for (int k = 0; k < 9; ++k)
        wb[((size_t)(b * 9 + k) * 64 + co) * 64 + ci] = f2bf(wv[k] * dm);
}

// ------------- kernel 2b: zero the pad border of xp -------------
__global__ void k_zeropad(ushort* __restrict__ xp) {
    int id = blockIdx.x * 256 + threadIdx.x;
    if (id >= 4 * 2052) return;
    int b = id / 2052, r = id % 2052;
    int gyp, gxp;
    if (r < 514)       { gyp = 0;        gxp = r; }
    else if (r < 1028) { gyp = 513;      gxp = r - 514; }
    else if (r < 1540) { gyp = r - 1027; gxp = 0; }
    else               { gyp = r - 1539; gxp = 513; }
    ushort* p = xp + (((size_t)b * PW + gyp) * PW + gxp) * 64;
    uint4 z = make_uint4(0, 0, 0, 0);
    #pragma unroll
    for (int i = 0; i < 8; ++i) *(uint4*)(p + i * 8) = z;
}

// ------------- kernel 2c: x fp32 [b][ci][H][W] -> xp bf16 [b][gy+1][gx+1][ci] -------------
// Block: 256 thr; handles 64 ci x 128 px of one row gy. LDS transpose.
__global__ __launch_bounds__(256) void k_xpose(
    const float* __restrict__ x, ushort* __restrict__ xp) {
    __shared__ ushort lt[128 * 68];
    const int t = threadIdx.x;
    const int bid = blockIdx.x;          // 4 b x 512 gy x 4 gxt
    const int gxt = bid & 3;
    const int gy  = (bid >> 2) & 511;
    const int b   = bid >> 11;

    const float* xb = x + (size_t)b * 64 * HW + (size_t)gy * WW + gxt * 128;
    const int ci0 = 8 * (t >> 5);
    const int gxc = t & 31;

    f32x4 v[8];
    #pragma unroll
    for (int j = 0; j < 8; ++j)
        v[j] = *(const f32x4*)(xb + (size_t)(ci0 + j) * HW + gxc * 4);

    // LDS layout: row'(px) = (px&3)*32 + (px>>2), stride 68 hw -> write-free banks
    #pragma unroll
    for (int p = 0; p < 4; ++p) {
        int px = gxc * 4 + p;
        int rowp = ((px & 3) * 32 + (px >> 2)) * 68;
        #pragma unroll
        for (int cg = 0; cg < 2; ++cg) {
            uint lo = cvtpk(v[4 * cg + 0][p], v[4 * cg + 1][p]);
            uint hi = cvtpk(v[4 * cg + 2][p], v[4 * cg + 3][p]);
            *(uint2*)&lt[rowp + ci0 + 4 * cg] = make_uint2(lo, hi);
        }
    }
    __syncthreads();

    const int px = t >> 1, half = t & 1;
    const int rowp = ((px & 3) * 32 + (px >> 2)) * 68 + half * 32;
    uint4 o0 = *(uint4*)&lt[rowp + 0];
    uint4 o1 = *(uint4*)&lt[rowp + 8];
    uint4 o2 = *(uint4*)&lt[rowp + 16];
    uint4 o3 = *(uint4*)&lt[rowp + 24];
    ushort* dst = xp + (((size_t)b * PW + (gy + 1)) * PW + (gxt * 128 + px + 1)) * 64
                     + half * 32;
    *(uint4*)(dst + 0)  = o0;
    *(uint4*)(dst + 8)  = o1;
    *(uint4*)(dst + 16) = o2;
    *(uint4*)(dst + 24) = o3;
}

// ------------- kernel 3: MFMA implicit-GEMM conv + epilogue -------------
// Block: 256 threads (4 waves). Output tile: 64 co x (8 rows x 32 cols).
// Staging: 43 x global_load_lds (1KB, bf16, contiguous) direct into
// tile[row 10][lcol 34][ci 64]; swizzle via pre-swizzled SOURCE address
// (content at ci-slot g is global group g ^ (lcol&7)) -> R2-proven
// conflict-free read pattern.
__global__ __launch_bounds__(256, 2) void k_conv(
    const ushort* __restrict__ xp,    // [4][514][514][64] bf16 padded
    const ushort* __restrict__ wb,    // [4][9][64][64] bf16
    const float* __restrict__ noise,  // [4][1][512][512]
    const float* __restrict__ bias,   // [64]
    float* __restrict__ out) {        // [4][64][512][512] fp32
    __shared__ ushort tile[2752 * 8];   // 44032 B (2720 used + slack)

    const int t = threadIdx.x;
    const int b = blockIdx.y;
    const int colb = blockIdx.x & 15;
    const int rowb = blockIdx.x >> 4;
    const int tx = colb * 32, ty = rowb * 8;
    const int w = t >> 6;
    const int lane = t & 63;

    const ushort* xpb = xp + (size_t)b * PPIX * 64;

    // ---- staging: 43 x 1KB global_load_lds, ~11 per wave ----
    for (int j = w; j < 43; j += 4) {
        int c = j * 64 + lane;
        int c2 = c < 2719 ? c : 2719;      // clamp garbage lanes in-bounds
        int cig = c2 & 7;
        int pxl = c2 >> 3;
        int row = pxl / 34;
        int lcol = pxl - row * 34;
        int gsrc = cig ^ (lcol & 7);       // pre-swizzled source ci-group
        const ushort* src = xpb + ((size_t)(ty + row) * PW + (tx + lcol)) * 64 + gsrc * 8;
        __builtin_amdgcn_global_load_lds(
            (const __attribute__((address_space(1))) unsigned int*)src,
            (__attribute__((address_space(3))) unsigned int*)&tile[j * 512],
            16, 0, 0);
    }
    asm volatile("s_waitcnt vmcnt(0)" ::: "memory");
    __syncthreads();

    // ---- compute (R2-proven mapping) ----
    const int lr = lane & 15;
    const int lq = lane >> 4;

    int bidx[4][3];
    #pragma unroll
    for (int i = 0; i < 4; ++i) {
        int nt = 4 * w + i;
        int prow = nt >> 1;
        int c = (nt & 1) * 16 + lr;
        #pragma unroll
        for (int dx = 0; dx < 3; ++dx) {
            int lcol = c + dx;
            bidx[i][dx] = (prow * 34 + lcol) * 64 + ((lq * 8) ^ ((lcol & 7) << 3));
        }
    }

    const ushort* wbb = wb + (size_t)b * 9 * 4096 + lr * 64 + lq * 8;

    f32x4 acc[4][4];
    #pragma unroll
    for (int m = 0; m < 4; ++m)
        #pragma unroll
        for (int i = 0; i < 4; ++i) acc[m][i] = (f32x4){0.f, 0.f, 0.f, 0.f};

    #pragma unroll
    for (int dy = 0; dy < 3; ++dy) {
        #pragma unroll
        for (int dx = 0; dx < 3; ++dx) {
            #pragma unroll
            for (int kb = 0; kb < 2; ++kb) {
                const int off = dy * 3 + dx;
                bf16x8 afr[4], bfr[4];
                #pragma unroll
                for (int m = 0; m < 4; ++m)
                    afr[m] = *(const bf16x8*)(wbb + off * 4096 + m * 1024 + kb * 32);
                #pragma unroll
                for (int i = 0; i < 4; ++i) {
                    int idx = (bidx[i][dx] + dy * (34 * 64)) ^ (kb << 5);
                    bfr[i] = *(const bf16x8*)&tile[idx];
                }
                #pragma unroll
                for (int m = 0; m < 4; ++m)
                    #pragma unroll
                    for (int i = 0; i < 4; ++i)
                        acc[m][i] = __builtin_amdgcn_mfma_f32_16x16x32_bf16(
                            afr[m], bfr[i], acc[m][i], 0, 0, 0);
            }
        }
    }

    // ---- epilogue: +noise, +bias, lrelu*sqrt2, clamp, store ----
    const float* nz = noise + (size_t)b * HW;
    float nv[4];
    int gyv[4], gxv[4];
    #pragma unroll
    for (int i = 0; i < 4; ++i) {
        int nt = 4 * w + i;
        int prow = nt >> 1;
        int pcol = (nt & 1) * 16 + lr;
        gyv[i] = ty + prow;
        gxv[i] = tx + pcol;
        nv[i] = nz[gyv[i] * WW + gxv[i]];
    }
    #pragma unroll
    for (int m = 0; m < 4; ++m) {
        f32x4 bv = *(const f32x4*)&bias[m * 16 + lq * 4];
        #pragma unroll
        for (int i = 0; i < 4; ++i) {
            #pragma unroll
            for (int rg2 = 0; rg2 < 4; ++rg2) {
                int co = m * 16 + lq * 4 + rg2;
                float y = acc[m][i][rg2] + nv[i] + bv[rg2];
                y = (y >= 0.f ? y : 0.2f * y) * 1.41421356237f;
                y = fminf(fmaxf(y, -256.f), 256.f);
                out[((size_t)(b * 64 + co) * HH + gyv[i]) * WW + gxv[i]] = y;
            }
        }
    }
}

extern "C" void kernel_launch(void* const* d_in, const int* in_sizes, int n_in,
                              void* d_out, int out_size, void* d_ws, size_t ws_size,
                              hipStream_t stream) {
    const float* x     = (const float*)d_in[0];
    const float* wsv   = (const float*)d_in[1];
    const float* noise = (const float*)d_in[2];
    const float* aw    = (const float*)d_in[3];
    const float* ab    = (const float*)d_in[4];
    const float* cw    = (const float*)d_in[5];
    const float* bias  = (const float*)d_in[6];
    float* out = (float*)d_out;

    float*  styles = (float*)d_ws;                          // 1 KB
    ushort* wb16   = (ushort*)((char*)d_ws + 1024);         // 294912 B
    ushort* xpad   = (ushort*)((char*)d_ws + (1 << 20));    // 135.3 MB

    k_styles<<<256, 64, 0, stream>>>(wsv, aw, ab, styles);
    k_wmod<<<256, 64, 0, stream>>>(cw, styles, wb16);
    k_zeropad<<<33, 256, 0, stream>>>(xpad);
    k_xpose<<<8192, 256, 0, stream>>>(x, xpad);
    dim3 grid(1024, 4);
    k_conv<<<grid, 256, 0, stream>>>(xpad, wb16, noise, bias, out);
}